// Round 7
// baseline (436.591 us; speedup 1.0000x reference)
//
#include <hip/hip_runtime.h>
#include <stdint.h>

// VQ-VAE vector quantizer — fp32, NCHW input [64,64,32,32], emb [1024,64].
// r24 = R6 (114.5us best: 3 kernels, no fence, swapped-operand MFMA core)
// with the TWO SWEEPS FUSED into one: margin is computable pre-sweep (A+maxC),
// so candidates are collected during the single MFMA pass under a RUNNING
// threshold (s >= m_run - margin, a superset of the final thr = gm - margin).
// Per-(lane,g) 4-slot u32 lists (monotone-bf16-key<<16 | idx), replace-min
// eviction (evict only when provably below final thr: stored < m_run-mar-eps);
// non-evictable displacement -> sticky overflow -> exact full-scan (existing
// path). Rescue filters vs exact thr (conservative) then exact-evals as now.
// Eliminates sweep 2 entirely: 128 MFMAs + 16 E-chunk loads + extraction.
constexpr int KCODES = 1024;
constexpr int DDIM   = 64;
constexpr int HW     = 1024;
constexpr int NPTS   = 65536;
constexpr int PPB    = 64;            // points per block
constexpr int NBLK   = NPTS / PPB;    // 1024

constexpr int OUT_IDX  = 4194304;
constexpr int OUT_LOSS = 4259840;
constexpr int OUT_NLL  = 4259841;

// ws 32-bit-unit offsets
constexpr int WS_MAXC  = 0;       // 16 f  : per-init-block max C
constexpr int WS_C     = 16;      // 1024 f: exact np C_k
constexpr int WS_E     = 2048;    // 32768 u32: SWIZZLED bf16-E (64 chunks x 2KB)
constexpr int WS_PART  = 34816;   // 1024 f: per-block loss partials

typedef __attribute__((ext_vector_type(8))) short short8v;
typedef __attribute__((ext_vector_type(4))) float float4v;

__device__ __forceinline__ uint16_t f2bf(float f) {   // RNE fp32->bf16
    uint32_t u = __float_as_uint(f);
    return (uint16_t)((u + 0x7fffu + ((u >> 16) & 1u)) >> 16);
}
__device__ __forceinline__ uint32_t pack2bf(float a, float b) {
    return (uint32_t)f2bf(a) | ((uint32_t)f2bf(b) << 16);
}

// monotone u16 key for bf16 bits (u32 compare == float compare)
__device__ __forceinline__ uint32_t bf_key(uint16_t b) {
    return (uint32_t)b ^ (0x8000u + ((uint32_t)(b >> 15) * 0x7FFFu));
}
__device__ __forceinline__ float key_to_f32(uint32_t k16) {
    uint32_t bb = (k16 & 0x8000u) ? (k16 ^ 0x8000u) : (~k16 & 0xFFFFu);
    return __uint_as_float(bb << 16);
}

// 4-slot replace-min insert. Slots init 0 (= empty, filtered as -NaN).
// ovfg set when the displaced min is NOT provably evictable.
__device__ __forceinline__ void slot_insert(uint32_t& s0, uint32_t& s1,
                                            uint32_t& s2, uint32_t& s3,
                                            uint32_t& ovfg, float s, int idx,
                                            float mnew, float marE) {
    uint32_t key  = bf_key(f2bf(s));
    uint32_t slot = (key << 16) | (uint32_t)idx;
    uint32_t m01 = s0 < s1 ? s0 : s1;
    uint32_t m23 = s2 < s3 ? s2 : s3;
    uint32_t mm  = m01 < m23 ? m01 : m23;
    float mf = key_to_f32(mm >> 16);
    bool safe = (mm < 0x10000u) || (mf < mnew - marE);  // empty always safe
    ovfg |= safe ? 0u : 1u;
    bool p0 = (s0 == mm);
    bool p1 = !p0 && (s1 == mm);
    bool p2 = !p0 && !p1 && (s2 == mm);
    bool p3 = !(p0 || p1 || p2);
    s0 = p0 ? slot : s0;
    s1 = p1 ? slot : s1;
    s2 = p2 ? slot : s2;
    s3 = p3 ? slot : s3;
}

__device__ __forceinline__ float np_pairwise_sumsq64(const float* a) {
    float r[8];
    #pragma unroll
    for (int j = 0; j < 8; ++j) r[j] = __fmul_rn(a[j], a[j]);
    #pragma unroll
    for (int i = 8; i < 64; i += 8)
        #pragma unroll
        for (int j = 0; j < 8; ++j)
            r[j] = __fadd_rn(r[j], __fmul_rn(a[i + j], a[i + j]));
    return __fadd_rn(__fadd_rn(__fadd_rn(r[0], r[1]), __fadd_rn(r[2], r[3])),
                     __fadd_rn(__fadd_rn(r[4], r[5]), __fadd_rn(r[6], r[7])));
}

// 16 blocks x 64 threads: code k = blockIdx*64 + tid. Writes SWIZZLED E.
__global__ __launch_bounds__(64) void vq_init(const float* __restrict__ emb,
                                              float* __restrict__ ws) {
    const int k = blockIdx.x * 64 + threadIdx.x;
    float row[DDIM];
    const float4* src = (const float4*)(emb + (size_t)k * DDIM);
    #pragma unroll
    for (int j = 0; j < 16; ++j) ((float4*)row)[j] = src[j];
    float C = np_pairwise_sumsq64(row);
    ws[WS_C + k] = C;
    {
        const int c = k >> 4, col = k & 15;
        uint32_t* eb = (uint32_t*)ws + WS_E + c * 512;   // chunk base (u32)
        #pragma unroll
        for (int q = 0; q < 4; ++q) {
            uint32_t* d0 = eb + (q * 16 + col) * 4;          // b0 plane
            uint32_t* d1 = eb + 256 + (q * 16 + col) * 4;    // b1 plane
            #pragma unroll
            for (int j = 0; j < 4; ++j) {
                d0[j] = pack2bf(row[q * 8 + 2 * j],      row[q * 8 + 2 * j + 1]);
                d1[j] = pack2bf(row[32 + q * 8 + 2 * j], row[32 + q * 8 + 2 * j + 1]);
            }
        }
    }
    float m = C;
    #pragma unroll
    for (int off = 32; off > 0; off >>= 1) m = fmaxf(m, __shfl_down(m, off, 64));
    if (threadIdx.x == 0) ws[WS_MAXC + blockIdx.x] = m;
}

__global__ __launch_bounds__(256, 4) void vq_main(
        const float* __restrict__ inp, const float* __restrict__ emb,
        float* __restrict__ ws, float* __restrict__ out)
{
    __shared__ float    sAp[PPB][4];    // pairwise partials (r2j + r2j+1)
    __shared__ float    sA[PPB];
    __shared__ float    sMar[PPB];      // margin M
    __shared__ float    sMarE[PPB];     // M + eps (evict guard)
    __shared__ float    sEps[PPB];      // eps (filter guard)
    __shared__ float    sPart[4][PPB];
    __shared__ float    sThr[PPB];
    __shared__ uint32_t sSlot[16][PPB][4];  // [wave*4+quad][point][slot]
    __shared__ uint8_t  sOvf[16][PPB];
    __shared__ int      sWin[PPB];
    __shared__ float    sred[4];

    const int tid  = threadIdx.x;
    const int lane = tid & 63;
    const int wave = tid >> 6;          // = code quarter
    const int col  = lane & 15;         // = POINT within 16-group (swapped layout)
    const int quad = lane >> 4;         // = code sub-quad (rows quad*4+r)
    const int base = blockIdx.x * PPB;
    const int b    = base >> 10;
    const int hw0  = base & 1023;

    // ---- prologue: exact-A partials, 4 threads per point (bit-exact tree
    //      split of np pairwise: this thread computes r_{2j}+r_{2j+1}) -------
    {
        const int pp = tid >> 2;            // point
        const int jj = (tid & 3) * 2;       // r-pair base
        const float* xin = inp + (size_t)b * DDIM * HW + (hw0 + pp);
        float r0, r1;
        {
            float v0 = xin[(size_t)jj * HW];
            float v1 = xin[(size_t)(jj + 1) * HW];
            r0 = __fmul_rn(v0, v0);
            r1 = __fmul_rn(v1, v1);
        }
        #pragma unroll
        for (int i = 8; i < 64; i += 8) {
            float v0 = xin[(size_t)(i + jj) * HW];
            float v1 = xin[(size_t)(i + jj + 1) * HW];
            r0 = __fadd_rn(r0, __fmul_rn(v0, v0));
            r1 = __fadd_rn(r1, __fmul_rn(v1, v1));
        }
        sAp[pp][tid & 3] = __fadd_rn(r0, r1);
    }

    // ---- X-fragments for 4 row-groups (R6-verified; MFMA B-operand) --------
    short8v a[4][2];
    #pragma unroll
    for (int g = 0; g < 4; ++g) {
        const float* xp = inp + (size_t)b * DDIM * HW + (hw0 + g * 16 + col);
        short8v t0, t1;
        #pragma unroll
        for (int j = 0; j < 8; ++j) {
            t0[j] = (short)f2bf(xp[(size_t)(quad * 8 + j) * HW]);
            t1[j] = (short)f2bf(xp[(size_t)(32 + quad * 8 + j) * HW]);
        }
        a[g][0] = t0; a[g][1] = t1;
    }
    __syncthreads();

    // ---- margin phase (pre-sweep; A and maxC suffice) ----------------------
    if (tid < PPB) {
        float A = __fadd_rn(__fadd_rn(sAp[tid][0], sAp[tid][1]),
                            __fadd_rn(sAp[tid][2], sAp[tid][3]));
        sA[tid] = A;
        float mc = ws[WS_MAXC];
        #pragma unroll
        for (int j = 1; j < 16; ++j) mc = fmaxf(mc, ws[WS_MAXC + j]);
        float sq = sqrtf(A) * sqrtf(mc);
        float M  = 0.015625f * sq + 6e-5f;                 // same margin as R6
        float E  = 0.0078125f * sq + 0.001953125f * mc;    // bf16-store bound
        sMar[tid]  = M;
        sMarE[tid] = M + E;
        sEps[tid]  = E;
    }
    __syncthreads();

    float marg[4], marE[4];
    #pragma unroll
    for (int g = 0; g < 4; ++g) {
        marg[g] = sMar[g * 16 + col];
        marE[g] = sMarE[g * 16 + col];
    }

    // swizzled E: lane reads its 16B at chunk*2048 + plane*1024 + lane*16 —
    // contiguous 1KB per wave-load; lane&15 indexes CODE -> valid A-fragment.
    const char* Eb = (const char*)((const uint32_t*)ws + WS_E);
    const char* Ew = Eb + (size_t)wave * 16 * 2048 + (size_t)lane * 16;
    const float* Cw = ws + WS_C;
    const int k0 = wave * 256;
    const float4v* Cq = (const float4v*)(ws + WS_C + k0);   // 16B-aligned

    // ---- FUSED sweep: score-max + running-threshold candidate collection ---
    float    m_run[4] = {-3.0e38f, -3.0e38f, -3.0e38f, -3.0e38f};
    uint32_t sl[4][4] = {{0,0,0,0},{0,0,0,0},{0,0,0,0},{0,0,0,0}};
    uint32_t ovf[4]   = {0,0,0,0};
    {
        short8v pa0 = *(const short8v*)(Ew);
        short8v pa1 = *(const short8v*)(Ew + 1024);
        short8v pb0 = *(const short8v*)(Ew + 2048);
        short8v pb1 = *(const short8v*)(Ew + 3072);
        float4v ca4 = Cq[quad];
        float4v cb4 = Cq[4 + quad];
        #pragma unroll 1
        for (int c2 = 0; c2 < 16; c2 += 2) {
            short8v u0 = pa0, u1 = pa1; float4v uc4 = ca4;
            if (c2 + 2 < 16) {
                const char* er = Ew + (size_t)(c2 + 2) * 2048;
                pa0 = *(const short8v*)(er);
                pa1 = *(const short8v*)(er + 1024);
                ca4 = Cq[(c2 + 2) * 4 + quad];
            }
            {
                float4v ci = {uc4[0] * -0.5f, uc4[1] * -0.5f,
                              uc4[2] * -0.5f, uc4[3] * -0.5f};
                const int kb = k0 + c2 * 16 + quad * 4;
                #pragma unroll
                for (int g = 0; g < 4; ++g) {
                    float4v acc = ci;
                    acc = __builtin_amdgcn_mfma_f32_16x16x32_bf16(u0, a[g][0], acc, 0, 0, 0);
                    acc = __builtin_amdgcn_mfma_f32_16x16x32_bf16(u1, a[g][1], acc, 0, 0, 0);
                    float m4 = fmaxf(fmaxf(acc[0], acc[1]), fmaxf(acc[2], acc[3]));
                    float mnew = fmaxf(m_run[g], m4);
                    m_run[g] = mnew;
                    if (__any(m4 >= mnew - marg[g])) {
                        #pragma unroll
                        for (int r = 0; r < 4; ++r)
                            if (acc[r] >= mnew - marg[g])
                                slot_insert(sl[g][0], sl[g][1], sl[g][2], sl[g][3],
                                            ovf[g], acc[r], kb + r, mnew, marE[g]);
                    }
                }
            }
            short8v v0 = pb0, v1 = pb1; float4v vc4 = cb4;
            if (c2 + 3 < 16) {
                const char* er = Ew + (size_t)(c2 + 3) * 2048;
                pb0 = *(const short8v*)(er);
                pb1 = *(const short8v*)(er + 1024);
                cb4 = Cq[(c2 + 3) * 4 + quad];
            }
            {
                float4v ci = {vc4[0] * -0.5f, vc4[1] * -0.5f,
                              vc4[2] * -0.5f, vc4[3] * -0.5f};
                const int kb = k0 + (c2 + 1) * 16 + quad * 4;
                #pragma unroll
                for (int g = 0; g < 4; ++g) {
                    float4v acc = ci;
                    acc = __builtin_amdgcn_mfma_f32_16x16x32_bf16(v0, a[g][0], acc, 0, 0, 0);
                    acc = __builtin_amdgcn_mfma_f32_16x16x32_bf16(v1, a[g][1], acc, 0, 0, 0);
                    float m4 = fmaxf(fmaxf(acc[0], acc[1]), fmaxf(acc[2], acc[3]));
                    float mnew = fmaxf(m_run[g], m4);
                    m_run[g] = mnew;
                    if (__any(m4 >= mnew - marg[g])) {
                        #pragma unroll
                        for (int r = 0; r < 4; ++r)
                            if (acc[r] >= mnew - marg[g])
                                slot_insert(sl[g][0], sl[g][1], sl[g][2], sl[g][3],
                                            ovf[g], acc[r], kb + r, mnew, marE[g]);
                    }
                }
            }
        }
    }
    // cross-quad reduce of score-max (identical to R6's gmax reduce)
    #pragma unroll
    for (int g = 0; g < 4; ++g) {
        float m = m_run[g];
        m = fmaxf(m, __shfl_xor(m, 16, 64));
        m = fmaxf(m, __shfl_xor(m, 32, 64));
        if (quad == 0) sPart[wave][g * 16 + col] = m;
    }
    // write candidate slots + overflow flags
    {
        const int wq = wave * 4 + quad;
        #pragma unroll
        for (int g = 0; g < 4; ++g) {
            uint32_t* d = &sSlot[wq][g * 16 + col][0];
            d[0] = sl[g][0]; d[1] = sl[g][1]; d[2] = sl[g][2]; d[3] = sl[g][3];
            sOvf[wq][g * 16 + col] = (uint8_t)ovf[g];
        }
    }
    __syncthreads();

    // ---- per-point exact threshold ----------------------------------------
    if (tid < PPB) {
        float gm = fmaxf(fmaxf(sPart[0][tid], sPart[1][tid]),
                         fmaxf(sPart[2][tid], sPart[3][tid]));
        sThr[tid] = gm - sMar[tid];
    }
    __syncthreads();

    // ---- rescue: filter slots vs thr (conservative), exact np-fp32 eval ----
    if (tid < PPB) {
        const int p = tid, n = base + p;
        const float thrE = sThr[p] - sEps[p];
        bool ovfAny = false;
        #pragma unroll
        for (int wq = 0; wq < 16; ++wq) ovfAny |= (sOvf[wq][p] != 0);
        int tot = 0, first = 0;
        #pragma unroll 1
        for (int wq = 0; wq < 16; ++wq) {
            #pragma unroll
            for (int j = 0; j < 4; ++j) {
                uint32_t s = sSlot[wq][p][j];
                float f = key_to_f32(s >> 16);
                if (f >= thrE) { ++tot; if (tot == 1) first = (int)(s & 0xFFFFu); }
            }
        }
        int win;
        if (!ovfAny && tot == 1) {
            win = first;
        } else if (!ovfAny && tot >= 2) {
            const float* xin = inp + (size_t)b * DDIM * HW + (hw0 + p);
            float x[DDIM];
            #pragma unroll
            for (int d = 0; d < DDIM; ++d) x[d] = xin[(size_t)d * HW];
            const float A = sA[p];
            float bd = 3.0e38f; win = KCODES - 1;
            #pragma unroll 1
            for (int wq = 0; wq < 16; ++wq) {
                #pragma unroll
                for (int j = 0; j < 4; ++j) {
                    uint32_t s = sSlot[wq][p][j];
                    float f = key_to_f32(s >> 16);
                    if (f >= thrE) {
                        int k = (int)(s & 0xFFFFu);
                        float e[DDIM];
                        const float4* e4 = (const float4*)(emb + (size_t)k * DDIM);
                        #pragma unroll
                        for (int jj = 0; jj < 16; ++jj) ((float4*)e)[jj] = e4[jj];
                        float g = 0.f;
                        #pragma unroll
                        for (int d = 0; d < DDIM; ++d) g = fmaf(x[d], e[d], g);
                        float dd = __fadd_rn(__fsub_rn(A, __fmul_rn(2.0f, g)), Cw[k]);
                        if (dd < bd || (dd == bd && k < win)) { bd = dd; win = k; }
                    }
                }
            }
        } else {                                    // overflow / safety
            const float* xin = inp + (size_t)b * DDIM * HW + (hw0 + p);
            float x[DDIM];
            #pragma unroll
            for (int d = 0; d < DDIM; ++d) x[d] = xin[(size_t)d * HW];
            const float A = sA[p];
            float bd = 3.0e38f; win = KCODES - 1;
            #pragma unroll 1
            for (int k = 0; k < KCODES; ++k) {
                float e[DDIM];
                const float4* e4 = (const float4*)(emb + (size_t)k * DDIM);
                #pragma unroll
                for (int j = 0; j < 16; ++j) ((float4*)e)[j] = e4[j];
                float g = 0.f;
                #pragma unroll
                for (int d = 0; d < DDIM; ++d) g = fmaf(x[d], e[d], g);
                float dd = __fadd_rn(__fsub_rn(A, __fmul_rn(2.0f, g)), Cw[k]);
                if (dd < bd) { bd = dd; win = k; }
            }
        }
        sWin[p] = win;
        out[OUT_IDX + n] = (float)win;
    }
    __syncthreads();

    // ---- epilogue: quantized NCHW + loss partial (plain store) -------------
    {
        const int pl = tid & 63, qtr = tid >> 6;
        const int win = sWin[pl];
        const int ch0 = qtr * 16;
        float q[16];
        const float4* q4 = (const float4*)(emb + (size_t)win * DDIM + ch0);
        #pragma unroll
        for (int j = 0; j < 4; ++j) ((float4*)q)[j] = q4[j];
        const size_t off = (size_t)b * DDIM * HW + (size_t)ch0 * HW + (hw0 + pl);
        const float* xin2 = inp + off;
        float* orow = out + off;
        float lacc = 0.f;
        #pragma unroll
        for (int j = 0; j < 16; ++j) {
            float xv = xin2[(size_t)j * HW];
            float diff = __fsub_rn(q[j], xv);
            orow[(size_t)j * HW] = __fadd_rn(xv, diff);   // ref's x + (q - x)
            lacc = fmaf(diff, diff, lacc);
        }
        #pragma unroll
        for (int o2 = 32; o2 > 0; o2 >>= 1) lacc += __shfl_down(lacc, o2, 64);
        if (lane == 0) sred[wave] = lacc;
    }
    __syncthreads();
    if (tid == 0)
        ws[WS_PART + blockIdx.x] = sred[0] + sred[1] + sred[2] + sred[3];
}

// 1 block x 256: reduce 1024 partials -> loss; write nll
__global__ __launch_bounds__(256) void vq_fin(const float* __restrict__ ws,
                                              float* __restrict__ out) {
    __shared__ float sred[4];
    const int tid = threadIdx.x;
    float s = 0.f;
    #pragma unroll
    for (int j = 0; j < 4; ++j) s += ws[WS_PART + j * 256 + tid];
    #pragma unroll
    for (int off = 32; off > 0; off >>= 1) s += __shfl_down(s, off, 64);
    if ((tid & 63) == 0) sred[tid >> 6] = s;
    __syncthreads();
    if (tid == 0) {
        float L = sred[0] + sred[1] + sred[2] + sred[3];
        out[OUT_LOSS] = L * (1.25f / 4194304.0f);   // (1+CC)*mean over N*D
        out[OUT_NLL]  = 1.0f;
    }
}

extern "C" void kernel_launch(void* const* d_in, const int* in_sizes, int n_in,
                              void* d_out, int out_size, void* d_ws, size_t ws_size,
                              hipStream_t stream) {
    const float* inp = (const float*)d_in[0];
    const float* emb = (const float*)d_in[1];
    float* out = (float*)d_out;
    float* ws  = (float*)d_ws;

    vq_init<<<16, 64, 0, stream>>>(emb, ws);
    vq_main<<<NBLK, 256, 0, stream>>>(inp, emb, ws, out);
    vq_fin<<<1, 256, 0, stream>>>(ws, out);
}

// Round 8
// 140.869 us; speedup vs baseline: 3.0993x; 3.0993x over previous
//
#include <hip/hip_runtime.h>
#include <stdint.h>

// VQ-VAE vector quantizer — fp32, NCHW input [64,64,32,32], emb [1024,64].
// r25 = R6 (114.5us best: 3 kernels, swapped-operand MFMA, per-lane u64
// candidate lists, fixed-threshold sweep-2 branch) widened to 8 waves/block:
// each wave sweeps a 128-code eighth (c2<8), grid stays 1024 -> 4 blk/CU x
// 8 waves = 32 waves/CU (was 16, occupancy 33%). R2's version of this died
// from __launch_bounds__(512,8) -> VGPR=32 -> spill; here bounds(512,2)
// leaves the allocator at R6's natural ~64 VGPR. All numeric paths are
// round-verified: 8-slot np A-split (R19/R20), tid<256 epilogue (R19),
// swapped sweep core verbatim (R6). R7 lesson honored: NO loop-carried
// data-dependent state in the MFMA loop (threshold stays loop-invariant).
constexpr int KCODES = 1024;
constexpr int DDIM   = 64;
constexpr int HW     = 1024;
constexpr int NPTS   = 65536;
constexpr int PPB    = 64;            // points per block
constexpr int NBLK   = NPTS / PPB;    // 1024
constexpr int NWAVE  = 8;             // waves per block

constexpr int OUT_IDX  = 4194304;
constexpr int OUT_LOSS = 4259840;
constexpr int OUT_NLL  = 4259841;

// ws 32-bit-unit offsets
constexpr int WS_MAXC  = 0;       // 16 f  : per-init-block max C
constexpr int WS_C     = 16;      // 1024 f: exact np C_k
constexpr int WS_E     = 2048;    // 32768 u32: SWIZZLED bf16-E (64 chunks x 2KB)
constexpr int WS_PART  = 34816;   // 1024 f: per-block loss partials

typedef __attribute__((ext_vector_type(8))) short short8v;
typedef __attribute__((ext_vector_type(4))) float float4v;

__device__ __forceinline__ uint16_t f2bf(float f) {   // RNE fp32->bf16
    uint32_t u = __float_as_uint(f);
    return (uint16_t)((u + 0x7fffu + ((u >> 16) & 1u)) >> 16);
}
__device__ __forceinline__ uint32_t pack2bf(float a, float b) {
    return (uint32_t)f2bf(a) | ((uint32_t)f2bf(b) << 16);
}

__device__ __forceinline__ float np_pairwise_sumsq64(const float* a) {
    float r[8];
    #pragma unroll
    for (int j = 0; j < 8; ++j) r[j] = __fmul_rn(a[j], a[j]);
    #pragma unroll
    for (int i = 8; i < 64; i += 8)
        #pragma unroll
        for (int j = 0; j < 8; ++j)
            r[j] = __fadd_rn(r[j], __fmul_rn(a[i + j], a[i + j]));
    return __fadd_rn(__fadd_rn(__fadd_rn(r[0], r[1]), __fadd_rn(r[2], r[3])),
                     __fadd_rn(__fadd_rn(r[4], r[5]), __fadd_rn(r[6], r[7])));
}

// 16 blocks x 64 threads: code k = blockIdx*64 + tid. Writes SWIZZLED E.
__global__ __launch_bounds__(64) void vq_init(const float* __restrict__ emb,
                                              float* __restrict__ ws) {
    const int k = blockIdx.x * 64 + threadIdx.x;
    float row[DDIM];
    const float4* src = (const float4*)(emb + (size_t)k * DDIM);
    #pragma unroll
    for (int j = 0; j < 16; ++j) ((float4*)row)[j] = src[j];
    float C = np_pairwise_sumsq64(row);
    ws[WS_C + k] = C;
    {
        const int c = k >> 4, col = k & 15;
        uint32_t* eb = (uint32_t*)ws + WS_E + c * 512;   // chunk base (u32)
        #pragma unroll
        for (int q = 0; q < 4; ++q) {
            uint32_t* d0 = eb + (q * 16 + col) * 4;          // b0 plane
            uint32_t* d1 = eb + 256 + (q * 16 + col) * 4;    // b1 plane
            #pragma unroll
            for (int j = 0; j < 4; ++j) {
                d0[j] = pack2bf(row[q * 8 + 2 * j],      row[q * 8 + 2 * j + 1]);
                d1[j] = pack2bf(row[32 + q * 8 + 2 * j], row[32 + q * 8 + 2 * j + 1]);
            }
        }
    }
    float m = C;
    #pragma unroll
    for (int off = 32; off > 0; off >>= 1) m = fmaxf(m, __shfl_down(m, off, 64));
    if (threadIdx.x == 0) ws[WS_MAXC + blockIdx.x] = m;
}

__global__ __launch_bounds__(512, 2) void vq_main(
        const float* __restrict__ inp, const float* __restrict__ emb,
        float* __restrict__ ws, float* __restrict__ out)
{
    __shared__ float    sAp[PPB][8];    // np 8-slot A partials (R19-verified)
    __shared__ float    sA[PPB];
    __shared__ float    sPart[NWAVE][PPB];
    __shared__ float    sThr[PPB];
    __shared__ unsigned long long sCandL[32][PPB];  // [wave*4+quad][point]
    __shared__ int      sCntL[32][PPB];
    __shared__ int      sWin[PPB];
    __shared__ float    sred[4];

    const int tid  = threadIdx.x;
    const int lane = tid & 63;
    const int wave = tid >> 6;          // = code eighth (0..7)
    const int col  = lane & 15;         // = POINT within 16-group (swapped layout)
    const int quad = lane >> 4;         // = code sub-quad (rows quad*4+r)
    const int base = blockIdx.x * PPB;
    const int b    = base >> 10;
    const int hw0  = base & 1023;

    // ---- prologue: exact-A 8-slot partials (np tree; R19/R20-verified).
    //      p = tid&63 -> 64 consecutive threads = consecutive hw -> coalesced.
    {
        const int pp  = tid & 63;           // point
        const int seg = tid >> 6;           // np slot j (0..7)
        const float* xin = inp + (size_t)b * DDIM * HW + (hw0 + pp);
        float v = xin[(size_t)seg * HW];
        float r = __fmul_rn(v, v);
        #pragma unroll
        for (int i = 1; i < 8; ++i) {
            float vv = xin[(size_t)(8 * i + seg) * HW];
            r = __fadd_rn(r, __fmul_rn(vv, vv));
        }
        sAp[pp][seg] = r;
    }

    // ---- X-fragments for 4 row-groups (R6-verified; MFMA B-operand) --------
    short8v a[4][2];
    #pragma unroll
    for (int g = 0; g < 4; ++g) {
        const float* xp = inp + (size_t)b * DDIM * HW + (hw0 + g * 16 + col);
        short8v t0, t1;
        #pragma unroll
        for (int j = 0; j < 8; ++j) {
            t0[j] = (short)f2bf(xp[(size_t)(quad * 8 + j) * HW]);
            t1[j] = (short)f2bf(xp[(size_t)(32 + quad * 8 + j) * HW]);
        }
        a[g][0] = t0; a[g][1] = t1;
    }

    // swizzled E: wave w reads chunks 8w..8w+7 (codes 128w..128w+127);
    // lane reads its 16B at chunk*2048 + plane*1024 + lane*16 — contiguous
    // 1KB per wave-load; lane&15 indexes CODE -> valid A-fragment.
    const char* Eb = (const char*)((const uint32_t*)ws + WS_E);
    const char* Ew = Eb + (size_t)wave * 8 * 2048 + (size_t)lane * 16;
    const float* Cw = ws + WS_C;
    const int k0 = wave * 128;
    const float4v* Cq = (const float4v*)(ws + WS_C + k0);   // 16B-aligned

    // ---- sweep 1: per-point score-max, per-lane (no shuffles in loop) -----
    float gmax[4] = {-3.0e38f, -3.0e38f, -3.0e38f, -3.0e38f};
    {
        short8v pa0 = *(const short8v*)(Ew);
        short8v pa1 = *(const short8v*)(Ew + 1024);
        short8v pb0 = *(const short8v*)(Ew + 2048);
        short8v pb1 = *(const short8v*)(Ew + 3072);
        float4v ca4 = Cq[quad];
        float4v cb4 = Cq[4 + quad];
        #pragma unroll 1
        for (int c2 = 0; c2 < 8; c2 += 2) {
            short8v u0 = pa0, u1 = pa1; float4v uc4 = ca4;
            if (c2 + 2 < 8) {
                const char* er = Ew + (size_t)(c2 + 2) * 2048;
                pa0 = *(const short8v*)(er);
                pa1 = *(const short8v*)(er + 1024);
                ca4 = Cq[(c2 + 2) * 4 + quad];
            }
            {
                float4v ci = {uc4[0] * -0.5f, uc4[1] * -0.5f,
                              uc4[2] * -0.5f, uc4[3] * -0.5f};
                #pragma unroll
                for (int g = 0; g < 4; ++g) {
                    float4v acc = ci;
                    acc = __builtin_amdgcn_mfma_f32_16x16x32_bf16(u0, a[g][0], acc, 0, 0, 0);
                    acc = __builtin_amdgcn_mfma_f32_16x16x32_bf16(u1, a[g][1], acc, 0, 0, 0);
                    gmax[g] = fmaxf(gmax[g],
                                    fmaxf(fmaxf(acc[0], acc[1]), fmaxf(acc[2], acc[3])));
                }
            }
            short8v v0 = pb0, v1 = pb1; float4v vc4 = cb4;
            if (c2 + 3 < 8) {
                const char* er = Ew + (size_t)(c2 + 3) * 2048;
                pb0 = *(const short8v*)(er);
                pb1 = *(const short8v*)(er + 1024);
                cb4 = Cq[(c2 + 3) * 4 + quad];
            }
            {
                float4v ci = {vc4[0] * -0.5f, vc4[1] * -0.5f,
                              vc4[2] * -0.5f, vc4[3] * -0.5f};
                #pragma unroll
                for (int g = 0; g < 4; ++g) {
                    float4v acc = ci;
                    acc = __builtin_amdgcn_mfma_f32_16x16x32_bf16(v0, a[g][0], acc, 0, 0, 0);
                    acc = __builtin_amdgcn_mfma_f32_16x16x32_bf16(v1, a[g][1], acc, 0, 0, 0);
                    gmax[g] = fmaxf(gmax[g],
                                    fmaxf(fmaxf(acc[0], acc[1]), fmaxf(acc[2], acc[3])));
                }
            }
        }
    }
    // cross-quad reduce: 2 shuffles
    #pragma unroll
    for (int g = 0; g < 4; ++g) {
        float m = gmax[g];
        m = fmaxf(m, __shfl_xor(m, 16, 64));
        m = fmaxf(m, __shfl_xor(m, 32, 64));
        if (quad == 0) sPart[wave][g * 16 + col] = m;
    }
    __syncthreads();

    // ---- per-point threshold (combine exact-A 8 slots, np tree) ------------
    if (tid < PPB) {
        float A = __fadd_rn(
            __fadd_rn(__fadd_rn(sAp[tid][0], sAp[tid][1]),
                      __fadd_rn(sAp[tid][2], sAp[tid][3])),
            __fadd_rn(__fadd_rn(sAp[tid][4], sAp[tid][5]),
                      __fadd_rn(sAp[tid][6], sAp[tid][7])));
        sA[tid] = A;
        float gm = fmaxf(
            fmaxf(fmaxf(sPart[0][tid], sPart[1][tid]),
                  fmaxf(sPart[2][tid], sPart[3][tid])),
            fmaxf(fmaxf(sPart[4][tid], sPart[5][tid]),
                  fmaxf(sPart[6][tid], sPart[7][tid])));
        float mc = ws[WS_MAXC];
        #pragma unroll
        for (int j = 1; j < 16; ++j) mc = fmaxf(mc, ws[WS_MAXC + j]);
        sThr[tid] = gm - (0.015625f * sqrtf(A) * sqrtf(mc) + 6e-5f);
    }
    __syncthreads();

    float thrg[4];
    #pragma unroll
    for (int g = 0; g < 4; ++g) thrg[g] = sThr[g * 16 + col];

    // ---- sweep 2: candidates via per-lane u64 register lists ---------------
    unsigned long long lst[4] = {0ull, 0ull, 0ull, 0ull};
    int cnt[4] = {0, 0, 0, 0};
    {
        short8v pa0 = *(const short8v*)(Ew);
        short8v pa1 = *(const short8v*)(Ew + 1024);
        short8v pb0 = *(const short8v*)(Ew + 2048);
        short8v pb1 = *(const short8v*)(Ew + 3072);
        float4v ca4 = Cq[quad];
        float4v cb4 = Cq[4 + quad];
        #pragma unroll 1
        for (int c2 = 0; c2 < 8; c2 += 2) {
            short8v u0 = pa0, u1 = pa1; float4v uc4 = ca4;
            if (c2 + 2 < 8) {
                const char* er = Ew + (size_t)(c2 + 2) * 2048;
                pa0 = *(const short8v*)(er);
                pa1 = *(const short8v*)(er + 1024);
                ca4 = Cq[(c2 + 2) * 4 + quad];
            }
            {
                float4v ci = {uc4[0] * -0.5f, uc4[1] * -0.5f,
                              uc4[2] * -0.5f, uc4[3] * -0.5f};
                const int kb = k0 + c2 * 16 + quad * 4;
                #pragma unroll
                for (int g = 0; g < 4; ++g) {
                    float4v acc = ci;
                    acc = __builtin_amdgcn_mfma_f32_16x16x32_bf16(u0, a[g][0], acc, 0, 0, 0);
                    acc = __builtin_amdgcn_mfma_f32_16x16x32_bf16(u1, a[g][1], acc, 0, 0, 0);
                    float m4 = fmaxf(fmaxf(acc[0], acc[1]), fmaxf(acc[2], acc[3]));
                    if (__any(m4 >= thrg[g])) {
                        #pragma unroll
                        for (int r = 0; r < 4; ++r) {
                            if (acc[r] >= thrg[g]) {
                                if (cnt[g] < 4)
                                    lst[g] |= (unsigned long long)(unsigned)(kb + r)
                                              << (cnt[g] << 4);
                                ++cnt[g];
                            }
                        }
                    }
                }
            }
            short8v v0 = pb0, v1 = pb1; float4v vc4 = cb4;
            if (c2 + 3 < 8) {
                const char* er = Ew + (size_t)(c2 + 3) * 2048;
                pb0 = *(const short8v*)(er);
                pb1 = *(const short8v*)(er + 1024);
                cb4 = Cq[(c2 + 3) * 4 + quad];
            }
            {
                float4v ci = {vc4[0] * -0.5f, vc4[1] * -0.5f,
                              vc4[2] * -0.5f, vc4[3] * -0.5f};
                const int kb = k0 + (c2 + 1) * 16 + quad * 4;
                #pragma unroll
                for (int g = 0; g < 4; ++g) {
                    float4v acc = ci;
                    acc = __builtin_amdgcn_mfma_f32_16x16x32_bf16(v0, a[g][0], acc, 0, 0, 0);
                    acc = __builtin_amdgcn_mfma_f32_16x16x32_bf16(v1, a[g][1], acc, 0, 0, 0);
                    float m4 = fmaxf(fmaxf(acc[0], acc[1]), fmaxf(acc[2], acc[3]));
                    if (__any(m4 >= thrg[g])) {
                        #pragma unroll
                        for (int r = 0; r < 4; ++r) {
                            if (acc[r] >= thrg[g]) {
                                if (cnt[g] < 4)
                                    lst[g] |= (unsigned long long)(unsigned)(kb + r)
                                              << (cnt[g] << 4);
                                ++cnt[g];
                            }
                        }
                    }
                }
            }
        }
    }
    {
        const int wq = wave * 4 + quad;
        #pragma unroll
        for (int g = 0; g < 4; ++g) {
            sCandL[wq][g * 16 + col] = lst[g];
            sCntL[wq][g * 16 + col]  = cnt[g];
        }
    }
    __syncthreads();

    // ---- rescue: exact np-fp32 on candidates -------------------------------
    if (tid < PPB) {
        const int p = tid, n = base + p;
        int tot = 0, cmax = 0;
        #pragma unroll
        for (int wq = 0; wq < 32; ++wq) {
            int c = sCntL[wq][p];
            tot += c;
            cmax = c > cmax ? c : cmax;
        }
        int win;
        if (tot == 1) {
            win = 0;
            #pragma unroll
            for (int wq = 0; wq < 32; ++wq)
                if (sCntL[wq][p]) win = (int)(sCandL[wq][p] & 0xffffu);
        } else {
            const float* xin = inp + (size_t)b * DDIM * HW + (hw0 + p);
            float x[DDIM];
            #pragma unroll
            for (int d = 0; d < DDIM; ++d) x[d] = xin[(size_t)d * HW];
            const float A = sA[p];
            float bd = 3.0e38f; win = KCODES - 1;
            if (cmax <= 4) {
                #pragma unroll 1
                for (int wq = 0; wq < 32; ++wq) {
                    int c = sCntL[wq][p];
                    unsigned long long L = sCandL[wq][p];
                    #pragma unroll 1
                    for (int i = 0; i < c; ++i) {
                        int k = (int)(L & 0xffffu);
                        L >>= 16;
                        float e[DDIM];
                        const float4* e4 = (const float4*)(emb + (size_t)k * DDIM);
                        #pragma unroll
                        for (int j = 0; j < 16; ++j) ((float4*)e)[j] = e4[j];
                        float g = 0.f;
                        #pragma unroll
                        for (int d = 0; d < DDIM; ++d) g = fmaf(x[d], e[d], g);
                        float dd = __fadd_rn(__fsub_rn(A, __fmul_rn(2.0f, g)), Cw[k]);
                        if (dd < bd || (dd == bd && k < win)) { bd = dd; win = k; }
                    }
                }
            } else {                                    // overflow safety
                #pragma unroll 1
                for (int k = 0; k < KCODES; ++k) {
                    float e[DDIM];
                    const float4* e4 = (const float4*)(emb + (size_t)k * DDIM);
                    #pragma unroll
                    for (int j = 0; j < 16; ++j) ((float4*)e)[j] = e4[j];
                    float g = 0.f;
                    #pragma unroll
                    for (int d = 0; d < DDIM; ++d) g = fmaf(x[d], e[d], g);
                    float dd = __fadd_rn(__fsub_rn(A, __fmul_rn(2.0f, g)), Cw[k]);
                    if (dd < bd) { bd = dd; win = k; }
                }
            }
        }
        sWin[p] = win;
        out[OUT_IDX + n] = (float)win;
    }
    __syncthreads();

    // ---- epilogue: quantized NCHW + loss partial (R19-verified tid<256) ----
    if (tid < 256) {
        const int pl = tid & 63, qtr = tid >> 6;
        const int win = sWin[pl];
        const int ch0 = qtr * 16;
        float q[16];
        const float4* q4 = (const float4*)(emb + (size_t)win * DDIM + ch0);
        #pragma unroll
        for (int j = 0; j < 4; ++j) ((float4*)q)[j] = q4[j];
        const size_t off = (size_t)b * DDIM * HW + (size_t)ch0 * HW + (hw0 + pl);
        const float* xin2 = inp + off;
        float* orow = out + off;
        float lacc = 0.f;
        #pragma unroll
        for (int j = 0; j < 16; ++j) {
            float xv = xin2[(size_t)j * HW];
            float diff = __fsub_rn(q[j], xv);
            orow[(size_t)j * HW] = __fadd_rn(xv, diff);   // ref's x + (q - x)
            lacc = fmaf(diff, diff, lacc);
        }
        #pragma unroll
        for (int o2 = 32; o2 > 0; o2 >>= 1) lacc += __shfl_down(lacc, o2, 64);
        if ((tid & 63) == 0) sred[qtr] = lacc;
    }
    __syncthreads();
    if (tid == 0)
        ws[WS_PART + blockIdx.x] = sred[0] + sred[1] + sred[2] + sred[3];
}

// 1 block x 256: reduce 1024 partials -> loss; write nll
__global__ __launch_bounds__(256) void vq_fin(const float* __restrict__ ws,
                                              float* __restrict__ out) {
    __shared__ float sred[4];
    const int tid = threadIdx.x;
    float s = 0.f;
    #pragma unroll
    for (int j = 0; j < 4; ++j) s += ws[WS_PART + j * 256 + tid];
    #pragma unroll
    for (int off = 32; off > 0; off >>= 1) s += __shfl_down(s, off, 64);
    if ((tid & 63) == 0) sred[tid >> 6] = s;
    __syncthreads();
    if (tid == 0) {
        float L = sred[0] + sred[1] + sred[2] + sred[3];
        out[OUT_LOSS] = L * (1.25f / 4194304.0f);   // (1+CC)*mean over N*D
        out[OUT_NLL]  = 1.0f;
    }
}

extern "C" void kernel_launch(void* const* d_in, const int* in_sizes, int n_in,
                              void* d_out, int out_size, void* d_ws, size_t ws_size,
                              hipStream_t stream) {
    const float* inp = (const float*)d_in[0];
    const float* emb = (const float*)d_in[1];
    float* out = (float*)d_out;
    float* ws  = (float*)d_ws;

    vq_init<<<16, 64, 0, stream>>>(emb, ws);
    vq_main<<<NBLK, 512, 0, stream>>>(inp, emb, ws, out);
    vq_fin<<<1, 256, 0, stream>>>(ws, out);
}

// Round 9
// 117.944 us; speedup vs baseline: 3.7017x; 1.1944x over previous
//
#include <hip/hip_runtime.h>
#include <stdint.h>

// VQ-VAE vector quantizer — fp32, NCHW input [64,64,32,32], emb [1024,64].
// r26 = R6 core (114.5us best: swapped-operand MFMA, per-lane u64 candidate
// lists, 3 kernels, no fence) at PPB=128: grid 512, 256 thr / 4 waves, each
// wave sweeps its 256-code quarter against 8 point-groups (a[8][2]).
// Mechanism (R3/R8 calibrated: per-wave fixed costs + E-amortization rule):
// E-loads per point halve, MFMA per c2-iter doubles (better latency cover),
// block fixed costs amortize 2x. bounds(256,2) (R2 lesson: no tight VGPR cap).
// Loss tree bit-exact: epilogue = two independent 64-point halves writing
// partials 2*bid+h -> same 1024 per-tile sums, vq_fin unchanged. A-split =
// exact np pairwise at the (r0..3)/(r4..7) level (2 threads/point).
constexpr int KCODES = 1024;
constexpr int DDIM   = 64;
constexpr int HW     = 1024;
constexpr int NPTS   = 65536;
constexpr int PPB    = 128;           // points per block
constexpr int NBLK   = NPTS / PPB;    // 512

constexpr int OUT_IDX  = 4194304;
constexpr int OUT_LOSS = 4259840;
constexpr int OUT_NLL  = 4259841;

// ws 32-bit-unit offsets
constexpr int WS_MAXC  = 0;       // 16 f  : per-init-block max C
constexpr int WS_C     = 16;      // 1024 f: exact np C_k
constexpr int WS_E     = 2048;    // 32768 u32: SWIZZLED bf16-E (64 chunks x 2KB)
constexpr int WS_PART  = 34816;   // 1024 f: per-64-point-tile loss partials

typedef __attribute__((ext_vector_type(8))) short short8v;
typedef __attribute__((ext_vector_type(4))) float float4v;

__device__ __forceinline__ uint16_t f2bf(float f) {   // RNE fp32->bf16
    uint32_t u = __float_as_uint(f);
    return (uint16_t)((u + 0x7fffu + ((u >> 16) & 1u)) >> 16);
}
__device__ __forceinline__ uint32_t pack2bf(float a, float b) {
    return (uint32_t)f2bf(a) | ((uint32_t)f2bf(b) << 16);
}

__device__ __forceinline__ float np_pairwise_sumsq64(const float* a) {
    float r[8];
    #pragma unroll
    for (int j = 0; j < 8; ++j) r[j] = __fmul_rn(a[j], a[j]);
    #pragma unroll
    for (int i = 8; i < 64; i += 8)
        #pragma unroll
        for (int j = 0; j < 8; ++j)
            r[j] = __fadd_rn(r[j], __fmul_rn(a[i + j], a[i + j]));
    return __fadd_rn(__fadd_rn(__fadd_rn(r[0], r[1]), __fadd_rn(r[2], r[3])),
                     __fadd_rn(__fadd_rn(r[4], r[5]), __fadd_rn(r[6], r[7])));
}

// 16 blocks x 64 threads: code k = blockIdx*64 + tid. Writes SWIZZLED E.
__global__ __launch_bounds__(64) void vq_init(const float* __restrict__ emb,
                                              float* __restrict__ ws) {
    const int k = blockIdx.x * 64 + threadIdx.x;
    float row[DDIM];
    const float4* src = (const float4*)(emb + (size_t)k * DDIM);
    #pragma unroll
    for (int j = 0; j < 16; ++j) ((float4*)row)[j] = src[j];
    float C = np_pairwise_sumsq64(row);
    ws[WS_C + k] = C;
    {
        const int c = k >> 4, col = k & 15;
        uint32_t* eb = (uint32_t*)ws + WS_E + c * 512;   // chunk base (u32)
        #pragma unroll
        for (int q = 0; q < 4; ++q) {
            uint32_t* d0 = eb + (q * 16 + col) * 4;          // b0 plane
            uint32_t* d1 = eb + 256 + (q * 16 + col) * 4;    // b1 plane
            #pragma unroll
            for (int j = 0; j < 4; ++j) {
                d0[j] = pack2bf(row[q * 8 + 2 * j],      row[q * 8 + 2 * j + 1]);
                d1[j] = pack2bf(row[32 + q * 8 + 2 * j], row[32 + q * 8 + 2 * j + 1]);
            }
        }
    }
    float m = C;
    #pragma unroll
    for (int off = 32; off > 0; off >>= 1) m = fmaxf(m, __shfl_down(m, off, 64));
    if (threadIdx.x == 0) ws[WS_MAXC + blockIdx.x] = m;
}

__global__ __launch_bounds__(256, 2) void vq_main(
        const float* __restrict__ inp, const float* __restrict__ emb,
        float* __restrict__ ws, float* __restrict__ out)
{
    __shared__ float    sAp[PPB][2];    // np half partials (r0..3)/(r4..7)
    __shared__ float    sA[PPB];
    __shared__ float    sPart[4][PPB];
    __shared__ float    sThr[PPB];
    __shared__ unsigned long long sCandL[16][PPB];  // [wave*4+quad][point]
    __shared__ int      sCntL[16][PPB];
    __shared__ int      sWin[PPB];
    __shared__ float    sred2[2][4];

    const int tid  = threadIdx.x;
    const int lane = tid & 63;
    const int wave = tid >> 6;          // = code quarter
    const int col  = lane & 15;         // = POINT within 16-group (swapped layout)
    const int quad = lane >> 4;         // = code sub-quad (rows quad*4+r)
    const int base = blockIdx.x * PPB;
    const int b    = base >> 10;
    const int hw0  = base & 1023;

    // ---- prologue: exact-A half partials, 2 threads per point (bit-exact
    //      np split: thread hh computes (r_{4hh}+r_{4hh+1})+(r_{4hh+2}+r_{4hh+3}))
    {
        const int pp = tid & 127;           // point (coalesced across lanes)
        const int hh = tid >> 7;            // half (0: r0..3, 1: r4..7)
        const int j0 = hh * 4;
        const float* xin = inp + (size_t)b * DDIM * HW + (hw0 + pp);
        float r0, r1, r2, r3;
        {
            float v0 = xin[(size_t)(j0 + 0) * HW];
            float v1 = xin[(size_t)(j0 + 1) * HW];
            float v2 = xin[(size_t)(j0 + 2) * HW];
            float v3 = xin[(size_t)(j0 + 3) * HW];
            r0 = __fmul_rn(v0, v0); r1 = __fmul_rn(v1, v1);
            r2 = __fmul_rn(v2, v2); r3 = __fmul_rn(v3, v3);
        }
        #pragma unroll
        for (int i = 8; i < 64; i += 8) {
            float v0 = xin[(size_t)(i + j0 + 0) * HW];
            float v1 = xin[(size_t)(i + j0 + 1) * HW];
            float v2 = xin[(size_t)(i + j0 + 2) * HW];
            float v3 = xin[(size_t)(i + j0 + 3) * HW];
            r0 = __fadd_rn(r0, __fmul_rn(v0, v0));
            r1 = __fadd_rn(r1, __fmul_rn(v1, v1));
            r2 = __fadd_rn(r2, __fmul_rn(v2, v2));
            r3 = __fadd_rn(r3, __fmul_rn(v3, v3));
        }
        sAp[pp][hh] = __fadd_rn(__fadd_rn(r0, r1), __fadd_rn(r2, r3));
    }

    // ---- X-fragments for 8 point-groups (R6-verified layout; MFMA B-op) ----
    short8v a[8][2];
    #pragma unroll
    for (int g = 0; g < 8; ++g) {
        const float* xp = inp + (size_t)b * DDIM * HW + (hw0 + g * 16 + col);
        short8v t0, t1;
        #pragma unroll
        for (int j = 0; j < 8; ++j) {
            t0[j] = (short)f2bf(xp[(size_t)(quad * 8 + j) * HW]);
            t1[j] = (short)f2bf(xp[(size_t)(32 + quad * 8 + j) * HW]);
        }
        a[g][0] = t0; a[g][1] = t1;
    }

    // swizzled E: lane reads its 16B at chunk*2048 + plane*1024 + lane*16 —
    // contiguous 1KB per wave-load; lane&15 indexes CODE -> valid A-fragment.
    const char* Eb = (const char*)((const uint32_t*)ws + WS_E);
    const char* Ew = Eb + (size_t)wave * 16 * 2048 + (size_t)lane * 16;
    const float* Cw = ws + WS_C;
    const int k0 = wave * 256;
    const float4v* Cq = (const float4v*)(ws + WS_C + k0);   // 16B-aligned

    // ---- sweep 1: per-point score-max, per-lane (no shuffles in loop) -----
    float gmax[8] = {-3.0e38f, -3.0e38f, -3.0e38f, -3.0e38f,
                     -3.0e38f, -3.0e38f, -3.0e38f, -3.0e38f};
    {
        short8v pa0 = *(const short8v*)(Ew);
        short8v pa1 = *(const short8v*)(Ew + 1024);
        short8v pb0 = *(const short8v*)(Ew + 2048);
        short8v pb1 = *(const short8v*)(Ew + 3072);
        float4v ca4 = Cq[quad];
        float4v cb4 = Cq[4 + quad];
        #pragma unroll 1
        for (int c2 = 0; c2 < 16; c2 += 2) {
            short8v u0 = pa0, u1 = pa1; float4v uc4 = ca4;
            if (c2 + 2 < 16) {
                const char* er = Ew + (size_t)(c2 + 2) * 2048;
                pa0 = *(const short8v*)(er);
                pa1 = *(const short8v*)(er + 1024);
                ca4 = Cq[(c2 + 2) * 4 + quad];
            }
            {
                float4v ci = {uc4[0] * -0.5f, uc4[1] * -0.5f,
                              uc4[2] * -0.5f, uc4[3] * -0.5f};
                #pragma unroll
                for (int g = 0; g < 8; ++g) {
                    float4v acc = ci;
                    acc = __builtin_amdgcn_mfma_f32_16x16x32_bf16(u0, a[g][0], acc, 0, 0, 0);
                    acc = __builtin_amdgcn_mfma_f32_16x16x32_bf16(u1, a[g][1], acc, 0, 0, 0);
                    gmax[g] = fmaxf(gmax[g],
                                    fmaxf(fmaxf(acc[0], acc[1]), fmaxf(acc[2], acc[3])));
                }
            }
            short8v v0 = pb0, v1 = pb1; float4v vc4 = cb4;
            if (c2 + 3 < 16) {
                const char* er = Ew + (size_t)(c2 + 3) * 2048;
                pb0 = *(const short8v*)(er);
                pb1 = *(const short8v*)(er + 1024);
                cb4 = Cq[(c2 + 3) * 4 + quad];
            }
            {
                float4v ci = {vc4[0] * -0.5f, vc4[1] * -0.5f,
                              vc4[2] * -0.5f, vc4[3] * -0.5f};
                #pragma unroll
                for (int g = 0; g < 8; ++g) {
                    float4v acc = ci;
                    acc = __builtin_amdgcn_mfma_f32_16x16x32_bf16(v0, a[g][0], acc, 0, 0, 0);
                    acc = __builtin_amdgcn_mfma_f32_16x16x32_bf16(v1, a[g][1], acc, 0, 0, 0);
                    gmax[g] = fmaxf(gmax[g],
                                    fmaxf(fmaxf(acc[0], acc[1]), fmaxf(acc[2], acc[3])));
                }
            }
        }
    }
    // cross-quad reduce: 2 shuffles per g
    #pragma unroll
    for (int g = 0; g < 8; ++g) {
        float m = gmax[g];
        m = fmaxf(m, __shfl_xor(m, 16, 64));
        m = fmaxf(m, __shfl_xor(m, 32, 64));
        if (quad == 0) sPart[wave][g * 16 + col] = m;
    }
    __syncthreads();

    // ---- per-point threshold (combine exact-A halves, np tree) -------------
    if (tid < PPB) {
        float A = __fadd_rn(sAp[tid][0], sAp[tid][1]);
        sA[tid] = A;
        float gm = fmaxf(fmaxf(sPart[0][tid], sPart[1][tid]),
                         fmaxf(sPart[2][tid], sPart[3][tid]));
        float mc = ws[WS_MAXC];
        #pragma unroll
        for (int j = 1; j < 16; ++j) mc = fmaxf(mc, ws[WS_MAXC + j]);
        sThr[tid] = gm - (0.015625f * sqrtf(A) * sqrtf(mc) + 6e-5f);
    }
    __syncthreads();

    float thrg[8];
    #pragma unroll
    for (int g = 0; g < 8; ++g) thrg[g] = sThr[g * 16 + col];

    // ---- sweep 2: candidates via per-lane u64 register lists ---------------
    unsigned long long lst[8] = {0,0,0,0,0,0,0,0};
    int cnt[8] = {0,0,0,0,0,0,0,0};
    {
        short8v pa0 = *(const short8v*)(Ew);
        short8v pa1 = *(const short8v*)(Ew + 1024);
        short8v pb0 = *(const short8v*)(Ew + 2048);
        short8v pb1 = *(const short8v*)(Ew + 3072);
        float4v ca4 = Cq[quad];
        float4v cb4 = Cq[4 + quad];
        #pragma unroll 1
        for (int c2 = 0; c2 < 16; c2 += 2) {
            short8v u0 = pa0, u1 = pa1; float4v uc4 = ca4;
            if (c2 + 2 < 16) {
                const char* er = Ew + (size_t)(c2 + 2) * 2048;
                pa0 = *(const short8v*)(er);
                pa1 = *(const short8v*)(er + 1024);
                ca4 = Cq[(c2 + 2) * 4 + quad];
            }
            {
                float4v ci = {uc4[0] * -0.5f, uc4[1] * -0.5f,
                              uc4[2] * -0.5f, uc4[3] * -0.5f};
                const int kb = k0 + c2 * 16 + quad * 4;
                #pragma unroll
                for (int g = 0; g < 8; ++g) {
                    float4v acc = ci;
                    acc = __builtin_amdgcn_mfma_f32_16x16x32_bf16(u0, a[g][0], acc, 0, 0, 0);
                    acc = __builtin_amdgcn_mfma_f32_16x16x32_bf16(u1, a[g][1], acc, 0, 0, 0);
                    float m4 = fmaxf(fmaxf(acc[0], acc[1]), fmaxf(acc[2], acc[3]));
                    if (__any(m4 >= thrg[g])) {
                        #pragma unroll
                        for (int r = 0; r < 4; ++r) {
                            if (acc[r] >= thrg[g]) {
                                if (cnt[g] < 4)
                                    lst[g] |= (unsigned long long)(unsigned)(kb + r)
                                              << (cnt[g] << 4);
                                ++cnt[g];
                            }
                        }
                    }
                }
            }
            short8v v0 = pb0, v1 = pb1; float4v vc4 = cb4;
            if (c2 + 3 < 16) {
                const char* er = Ew + (size_t)(c2 + 3) * 2048;
                pb0 = *(const short8v*)(er);
                pb1 = *(const short8v*)(er + 1024);
                cb4 = Cq[(c2 + 3) * 4 + quad];
            }
            {
                float4v ci = {vc4[0] * -0.5f, vc4[1] * -0.5f,
                              vc4[2] * -0.5f, vc4[3] * -0.5f};
                const int kb = k0 + (c2 + 1) * 16 + quad * 4;
                #pragma unroll
                for (int g = 0; g < 8; ++g) {
                    float4v acc = ci;
                    acc = __builtin_amdgcn_mfma_f32_16x16x32_bf16(v0, a[g][0], acc, 0, 0, 0);
                    acc = __builtin_amdgcn_mfma_f32_16x16x32_bf16(v1, a[g][1], acc, 0, 0, 0);
                    float m4 = fmaxf(fmaxf(acc[0], acc[1]), fmaxf(acc[2], acc[3]));
                    if (__any(m4 >= thrg[g])) {
                        #pragma unroll
                        for (int r = 0; r < 4; ++r) {
                            if (acc[r] >= thrg[g]) {
                                if (cnt[g] < 4)
                                    lst[g] |= (unsigned long long)(unsigned)(kb + r)
                                              << (cnt[g] << 4);
                                ++cnt[g];
                            }
                        }
                    }
                }
            }
        }
    }
    {
        const int wq = wave * 4 + quad;
        #pragma unroll
        for (int g = 0; g < 8; ++g) {
            sCandL[wq][g * 16 + col] = lst[g];
            sCntL[wq][g * 16 + col]  = cnt[g];
        }
    }
    __syncthreads();

    // ---- rescue: exact np-fp32 on candidates -------------------------------
    if (tid < PPB) {
        const int p = tid, n = base + p;
        int tot = 0, cmax = 0;
        #pragma unroll
        for (int wq = 0; wq < 16; ++wq) {
            int c = sCntL[wq][p];
            tot += c;
            cmax = c > cmax ? c : cmax;
        }
        int win;
        if (tot == 1) {
            win = 0;
            #pragma unroll
            for (int wq = 0; wq < 16; ++wq)
                if (sCntL[wq][p]) win = (int)(sCandL[wq][p] & 0xffffu);
        } else {
            const float* xin = inp + (size_t)b * DDIM * HW + (hw0 + p);
            float x[DDIM];
            #pragma unroll
            for (int d = 0; d < DDIM; ++d) x[d] = xin[(size_t)d * HW];
            const float A = sA[p];
            float bd = 3.0e38f; win = KCODES - 1;
            if (cmax <= 4) {
                #pragma unroll 1
                for (int wq = 0; wq < 16; ++wq) {
                    int c = sCntL[wq][p];
                    unsigned long long L = sCandL[wq][p];
                    #pragma unroll 1
                    for (int i = 0; i < c; ++i) {
                        int k = (int)(L & 0xffffu);
                        L >>= 16;
                        float e[DDIM];
                        const float4* e4 = (const float4*)(emb + (size_t)k * DDIM);
                        #pragma unroll
                        for (int j = 0; j < 16; ++j) ((float4*)e)[j] = e4[j];
                        float g = 0.f;
                        #pragma unroll
                        for (int d = 0; d < DDIM; ++d) g = fmaf(x[d], e[d], g);
                        float dd = __fadd_rn(__fsub_rn(A, __fmul_rn(2.0f, g)), Cw[k]);
                        if (dd < bd || (dd == bd && k < win)) { bd = dd; win = k; }
                    }
                }
            } else {                                    // overflow safety
                #pragma unroll 1
                for (int k = 0; k < KCODES; ++k) {
                    float e[DDIM];
                    const float4* e4 = (const float4*)(emb + (size_t)k * DDIM);
                    #pragma unroll
                    for (int j = 0; j < 16; ++j) ((float4*)e)[j] = e4[j];
                    float g = 0.f;
                    #pragma unroll
                    for (int d = 0; d < DDIM; ++d) g = fmaf(x[d], e[d], g);
                    float dd = __fadd_rn(__fsub_rn(A, __fmul_rn(2.0f, g)), Cw[k]);
                    if (dd < bd) { bd = dd; win = k; }
                }
            }
        }
        sWin[p] = win;
        out[OUT_IDX + n] = (float)win;
    }
    __syncthreads();

    // ---- epilogue: two independent 64-point halves, each = R6's epilogue ---
    #pragma unroll 1
    for (int h = 0; h < 2; ++h) {
        const int pl = tid & 63, qtr = tid >> 6;
        const int win = sWin[h * 64 + pl];
        const int ch0 = qtr * 16;
        float q[16];
        const float4* q4 = (const float4*)(emb + (size_t)win * DDIM + ch0);
        #pragma unroll
        for (int j = 0; j < 4; ++j) ((float4*)q)[j] = q4[j];
        const size_t off = (size_t)b * DDIM * HW + (size_t)ch0 * HW
                           + (hw0 + h * 64 + pl);
        const float* xin2 = inp + off;
        float* orow = out + off;
        float lacc = 0.f;
        #pragma unroll
        for (int j = 0; j < 16; ++j) {
            float xv = xin2[(size_t)j * HW];
            float diff = __fsub_rn(q[j], xv);
            orow[(size_t)j * HW] = __fadd_rn(xv, diff);   // ref's x + (q - x)
            lacc = fmaf(diff, diff, lacc);
        }
        #pragma unroll
        for (int o2 = 32; o2 > 0; o2 >>= 1) lacc += __shfl_down(lacc, o2, 64);
        if ((tid & 63) == 0) sred2[h][qtr] = lacc;
    }
    __syncthreads();
    if (tid == 0) {
        ws[WS_PART + 2 * blockIdx.x + 0] =
            sred2[0][0] + sred2[0][1] + sred2[0][2] + sred2[0][3];
        ws[WS_PART + 2 * blockIdx.x + 1] =
            sred2[1][0] + sred2[1][1] + sred2[1][2] + sred2[1][3];
    }
}

// 1 block x 256: reduce 1024 partials -> loss; write nll
__global__ __launch_bounds__(256) void vq_fin(const float* __restrict__ ws,
                                              float* __restrict__ out) {
    __shared__ float sred[4];
    const int tid = threadIdx.x;
    float s = 0.f;
    #pragma unroll
    for (int j = 0; j < 4; ++j) s += ws[WS_PART + j * 256 + tid];
    #pragma unroll
    for (int off = 32; off > 0; off >>= 1) s += __shfl_down(s, off, 64);
    if ((tid & 63) == 0) sred[tid >> 6] = s;
    __syncthreads();
    if (tid == 0) {
        float L = sred[0] + sred[1] + sred[2] + sred[3];
        out[OUT_LOSS] = L * (1.25f / 4194304.0f);   // (1+CC)*mean over N*D
        out[OUT_NLL]  = 1.0f;
    }
}

extern "C" void kernel_launch(void* const* d_in, const int* in_sizes, int n_in,
                              void* d_out, int out_size, void* d_ws, size_t ws_size,
                              hipStream_t stream) {
    const float* inp = (const float*)d_in[0];
    const float* emb = (const float*)d_in[1];
    float* out = (float*)d_out;
    float* ws  = (float*)d_ws;

    vq_init<<<16, 64, 0, stream>>>(emb, ws);
    vq_main<<<NBLK, 256, 0, stream>>>(inp, emb, ws, out);
    vq_fin<<<1, 256, 0, stream>>>(ws, out);
}

// Round 10
// 109.377 us; speedup vs baseline: 3.9916x; 1.0783x over previous
//
#include <hip/hip_runtime.h>
#include <stdint.h>

// VQ-VAE vector quantizer — fp32, NCHW input [64,64,32,32], emb [1024,64].
// r27 = R6 (114.5us best) with ONE change: the rescue is parallelized across
// the 4 waves. Previously tid<64 (wave 0) serially evaluated all candidates
// while waves 1-3 idled at the barrier; now wave w exact-evaluates the
// candidates it collected (wq=4w..4w+3, disjoint ascending k-ranges) for all
// 64 points, and a tid<64 combiner merges the 4 partial (bd,win) minima with
// the same ascending-k tie-break (equivalent to the global ascending scan).
// Per-candidate numerics byte-identical; tot==1 index-copy fast path and
// cmax>4 full-scan fallback unchanged in the combiner. +1 barrier.
// Sweeps / prologue / fragments / epilogue / init / fin: R6 verbatim.
constexpr int KCODES = 1024;
constexpr int DDIM   = 64;
constexpr int HW     = 1024;
constexpr int NPTS   = 65536;
constexpr int PPB    = 64;            // points per block
constexpr int NBLK   = NPTS / PPB;    // 1024

constexpr int OUT_IDX  = 4194304;
constexpr int OUT_LOSS = 4259840;
constexpr int OUT_NLL  = 4259841;

// ws 32-bit-unit offsets
constexpr int WS_MAXC  = 0;       // 16 f  : per-init-block max C
constexpr int WS_C     = 16;      // 1024 f: exact np C_k
constexpr int WS_E     = 2048;    // 32768 u32: SWIZZLED bf16-E (64 chunks x 2KB)
constexpr int WS_PART  = 34816;   // 1024 f: per-block loss partials

typedef __attribute__((ext_vector_type(8))) short short8v;
typedef __attribute__((ext_vector_type(4))) float float4v;

__device__ __forceinline__ uint16_t f2bf(float f) {   // RNE fp32->bf16
    uint32_t u = __float_as_uint(f);
    return (uint16_t)((u + 0x7fffu + ((u >> 16) & 1u)) >> 16);
}
__device__ __forceinline__ uint32_t pack2bf(float a, float b) {
    return (uint32_t)f2bf(a) | ((uint32_t)f2bf(b) << 16);
}

__device__ __forceinline__ float np_pairwise_sumsq64(const float* a) {
    float r[8];
    #pragma unroll
    for (int j = 0; j < 8; ++j) r[j] = __fmul_rn(a[j], a[j]);
    #pragma unroll
    for (int i = 8; i < 64; i += 8)
        #pragma unroll
        for (int j = 0; j < 8; ++j)
            r[j] = __fadd_rn(r[j], __fmul_rn(a[i + j], a[i + j]));
    return __fadd_rn(__fadd_rn(__fadd_rn(r[0], r[1]), __fadd_rn(r[2], r[3])),
                     __fadd_rn(__fadd_rn(r[4], r[5]), __fadd_rn(r[6], r[7])));
}

// 16 blocks x 64 threads: code k = blockIdx*64 + tid. Writes SWIZZLED E.
__global__ __launch_bounds__(64) void vq_init(const float* __restrict__ emb,
                                              float* __restrict__ ws) {
    const int k = blockIdx.x * 64 + threadIdx.x;
    float row[DDIM];
    const float4* src = (const float4*)(emb + (size_t)k * DDIM);
    #pragma unroll
    for (int j = 0; j < 16; ++j) ((float4*)row)[j] = src[j];
    float C = np_pairwise_sumsq64(row);
    ws[WS_C + k] = C;
    {
        const int c = k >> 4, col = k & 15;
        uint32_t* eb = (uint32_t*)ws + WS_E + c * 512;   // chunk base (u32)
        #pragma unroll
        for (int q = 0; q < 4; ++q) {
            uint32_t* d0 = eb + (q * 16 + col) * 4;          // b0 plane
            uint32_t* d1 = eb + 256 + (q * 16 + col) * 4;    // b1 plane
            #pragma unroll
            for (int j = 0; j < 4; ++j) {
                d0[j] = pack2bf(row[q * 8 + 2 * j],      row[q * 8 + 2 * j + 1]);
                d1[j] = pack2bf(row[32 + q * 8 + 2 * j], row[32 + q * 8 + 2 * j + 1]);
            }
        }
    }
    float m = C;
    #pragma unroll
    for (int off = 32; off > 0; off >>= 1) m = fmaxf(m, __shfl_down(m, off, 64));
    if (threadIdx.x == 0) ws[WS_MAXC + blockIdx.x] = m;
}

__global__ __launch_bounds__(256, 4) void vq_main(
        const float* __restrict__ inp, const float* __restrict__ emb,
        float* __restrict__ ws, float* __restrict__ out)
{
    __shared__ float    sAp[PPB][4];    // pairwise partials (r2j + r2j+1)
    __shared__ float    sA[PPB];
    __shared__ float    sPart[4][PPB];
    __shared__ float    sThr[PPB];
    __shared__ unsigned long long sCandL[16][PPB];  // [wave*4+quad][point]
    __shared__ int      sCntL[16][PPB];
    __shared__ float    sResB[4][PPB];  // per-wave partial min distance
    __shared__ int      sResW[4][PPB];  // per-wave partial argmin
    __shared__ int      sWin[PPB];
    __shared__ float    sred[4];

    const int tid  = threadIdx.x;
    const int lane = tid & 63;
    const int wave = tid >> 6;          // = code quarter
    const int col  = lane & 15;         // = POINT within 16-group (swapped layout)
    const int quad = lane >> 4;         // = code sub-quad (rows quad*4+r)
    const int base = blockIdx.x * PPB;
    const int b    = base >> 10;
    const int hw0  = base & 1023;

    // ---- prologue: exact-A partials, 4 threads per point (bit-exact tree
    //      split of np pairwise: this thread computes r_{2j}+r_{2j+1}) -------
    {
        const int pp = tid >> 2;            // point
        const int jj = (tid & 3) * 2;       // r-pair base
        const float* xin = inp + (size_t)b * DDIM * HW + (hw0 + pp);
        float r0, r1;
        {
            float v0 = xin[(size_t)jj * HW];
            float v1 = xin[(size_t)(jj + 1) * HW];
            r0 = __fmul_rn(v0, v0);
            r1 = __fmul_rn(v1, v1);
        }
        #pragma unroll
        for (int i = 8; i < 64; i += 8) {
            float v0 = xin[(size_t)(i + jj) * HW];
            float v1 = xin[(size_t)(i + jj + 1) * HW];
            r0 = __fadd_rn(r0, __fmul_rn(v0, v0));
            r1 = __fadd_rn(r1, __fmul_rn(v1, v1));
        }
        sAp[pp][tid & 3] = __fadd_rn(r0, r1);
    }

    // ---- X-fragments for 4 row-groups (unchanged; reused as MFMA B-op) ----
    short8v a[4][2];
    #pragma unroll
    for (int g = 0; g < 4; ++g) {
        const float* xp = inp + (size_t)b * DDIM * HW + (hw0 + g * 16 + col);
        short8v t0, t1;
        #pragma unroll
        for (int j = 0; j < 8; ++j) {
            t0[j] = (short)f2bf(xp[(size_t)(quad * 8 + j) * HW]);
            t1[j] = (short)f2bf(xp[(size_t)(32 + quad * 8 + j) * HW]);
        }
        a[g][0] = t0; a[g][1] = t1;
    }

    // swizzled E: lane reads its 16B at chunk*2048 + plane*1024 + lane*16 —
    // contiguous 1KB per wave-load; lane&15 indexes CODE -> valid A-fragment.
    const char* Eb = (const char*)((const uint32_t*)ws + WS_E);
    const char* Ew = Eb + (size_t)wave * 16 * 2048 + (size_t)lane * 16;
    const float* Cw = ws + WS_C;
    const int k0 = wave * 256;
    const float4v* Cq = (const float4v*)(ws + WS_C + k0);   // 16B-aligned

    // ---- sweep 1: per-point score-max, per-lane (no shuffles in loop) -----
    float gmax[4] = {-3.0e38f, -3.0e38f, -3.0e38f, -3.0e38f};
    {
        short8v pa0 = *(const short8v*)(Ew);
        short8v pa1 = *(const short8v*)(Ew + 1024);
        short8v pb0 = *(const short8v*)(Ew + 2048);
        short8v pb1 = *(const short8v*)(Ew + 3072);
        float4v ca4 = Cq[quad];
        float4v cb4 = Cq[4 + quad];
        #pragma unroll 1
        for (int c2 = 0; c2 < 16; c2 += 2) {
            short8v u0 = pa0, u1 = pa1; float4v uc4 = ca4;
            if (c2 + 2 < 16) {
                const char* er = Ew + (size_t)(c2 + 2) * 2048;
                pa0 = *(const short8v*)(er);
                pa1 = *(const short8v*)(er + 1024);
                ca4 = Cq[(c2 + 2) * 4 + quad];
            }
            {
                float4v ci = {uc4[0] * -0.5f, uc4[1] * -0.5f,
                              uc4[2] * -0.5f, uc4[3] * -0.5f};
                #pragma unroll
                for (int g = 0; g < 4; ++g) {
                    float4v acc = ci;
                    acc = __builtin_amdgcn_mfma_f32_16x16x32_bf16(u0, a[g][0], acc, 0, 0, 0);
                    acc = __builtin_amdgcn_mfma_f32_16x16x32_bf16(u1, a[g][1], acc, 0, 0, 0);
                    gmax[g] = fmaxf(gmax[g],
                                    fmaxf(fmaxf(acc[0], acc[1]), fmaxf(acc[2], acc[3])));
                }
            }
            short8v v0 = pb0, v1 = pb1; float4v vc4 = cb4;
            if (c2 + 3 < 16) {
                const char* er = Ew + (size_t)(c2 + 3) * 2048;
                pb0 = *(const short8v*)(er);
                pb1 = *(const short8v*)(er + 1024);
                cb4 = Cq[(c2 + 3) * 4 + quad];
            }
            {
                float4v ci = {vc4[0] * -0.5f, vc4[1] * -0.5f,
                              vc4[2] * -0.5f, vc4[3] * -0.5f};
                #pragma unroll
                for (int g = 0; g < 4; ++g) {
                    float4v acc = ci;
                    acc = __builtin_amdgcn_mfma_f32_16x16x32_bf16(v0, a[g][0], acc, 0, 0, 0);
                    acc = __builtin_amdgcn_mfma_f32_16x16x32_bf16(v1, a[g][1], acc, 0, 0, 0);
                    gmax[g] = fmaxf(gmax[g],
                                    fmaxf(fmaxf(acc[0], acc[1]), fmaxf(acc[2], acc[3])));
                }
            }
        }
    }
    // cross-quad reduce: 2 shuffles
    #pragma unroll
    for (int g = 0; g < 4; ++g) {
        float m = gmax[g];
        m = fmaxf(m, __shfl_xor(m, 16, 64));
        m = fmaxf(m, __shfl_xor(m, 32, 64));
        if (quad == 0) sPart[wave][g * 16 + col] = m;
    }
    __syncthreads();

    // ---- per-point threshold (also combine exact-A partials, exact tree) ---
    if (tid < PPB) {
        float A = __fadd_rn(__fadd_rn(sAp[tid][0], sAp[tid][1]),
                            __fadd_rn(sAp[tid][2], sAp[tid][3]));
        sA[tid] = A;
        float gm = fmaxf(fmaxf(sPart[0][tid], sPart[1][tid]),
                         fmaxf(sPart[2][tid], sPart[3][tid]));
        float mc = ws[WS_MAXC];
        #pragma unroll
        for (int j = 1; j < 16; ++j) mc = fmaxf(mc, ws[WS_MAXC + j]);
        sThr[tid] = gm - (0.015625f * sqrtf(A) * sqrtf(mc) + 6e-5f);
    }
    __syncthreads();

    float thrg[4];
    #pragma unroll
    for (int g = 0; g < 4; ++g) thrg[g] = sThr[g * 16 + col];

    // ---- sweep 2: candidates via per-lane u64 register lists ---------------
    unsigned long long lst[4] = {0ull, 0ull, 0ull, 0ull};
    int cnt[4] = {0, 0, 0, 0};
    {
        short8v pa0 = *(const short8v*)(Ew);
        short8v pa1 = *(const short8v*)(Ew + 1024);
        short8v pb0 = *(const short8v*)(Ew + 2048);
        short8v pb1 = *(const short8v*)(Ew + 3072);
        float4v ca4 = Cq[quad];
        float4v cb4 = Cq[4 + quad];
        #pragma unroll 1
        for (int c2 = 0; c2 < 16; c2 += 2) {
            short8v u0 = pa0, u1 = pa1; float4v uc4 = ca4;
            if (c2 + 2 < 16) {
                const char* er = Ew + (size_t)(c2 + 2) * 2048;
                pa0 = *(const short8v*)(er);
                pa1 = *(const short8v*)(er + 1024);
                ca4 = Cq[(c2 + 2) * 4 + quad];
            }
            {
                float4v ci = {uc4[0] * -0.5f, uc4[1] * -0.5f,
                              uc4[2] * -0.5f, uc4[3] * -0.5f};
                const int kb = k0 + c2 * 16 + quad * 4;
                #pragma unroll
                for (int g = 0; g < 4; ++g) {
                    float4v acc = ci;
                    acc = __builtin_amdgcn_mfma_f32_16x16x32_bf16(u0, a[g][0], acc, 0, 0, 0);
                    acc = __builtin_amdgcn_mfma_f32_16x16x32_bf16(u1, a[g][1], acc, 0, 0, 0);
                    float m4 = fmaxf(fmaxf(acc[0], acc[1]), fmaxf(acc[2], acc[3]));
                    if (__any(m4 >= thrg[g])) {
                        #pragma unroll
                        for (int r = 0; r < 4; ++r) {
                            if (acc[r] >= thrg[g]) {
                                if (cnt[g] < 4)
                                    lst[g] |= (unsigned long long)(unsigned)(kb + r)
                                              << (cnt[g] << 4);
                                ++cnt[g];
                            }
                        }
                    }
                }
            }
            short8v v0 = pb0, v1 = pb1; float4v vc4 = cb4;
            if (c2 + 3 < 16) {
                const char* er = Ew + (size_t)(c2 + 3) * 2048;
                pb0 = *(const short8v*)(er);
                pb1 = *(const short8v*)(er + 1024);
                cb4 = Cq[(c2 + 3) * 4 + quad];
            }
            {
                float4v ci = {vc4[0] * -0.5f, vc4[1] * -0.5f,
                              vc4[2] * -0.5f, vc4[3] * -0.5f};
                const int kb = k0 + (c2 + 1) * 16 + quad * 4;
                #pragma unroll
                for (int g = 0; g < 4; ++g) {
                    float4v acc = ci;
                    acc = __builtin_amdgcn_mfma_f32_16x16x32_bf16(v0, a[g][0], acc, 0, 0, 0);
                    acc = __builtin_amdgcn_mfma_f32_16x16x32_bf16(v1, a[g][1], acc, 0, 0, 0);
                    float m4 = fmaxf(fmaxf(acc[0], acc[1]), fmaxf(acc[2], acc[3]));
                    if (__any(m4 >= thrg[g])) {
                        #pragma unroll
                        for (int r = 0; r < 4; ++r) {
                            if (acc[r] >= thrg[g]) {
                                if (cnt[g] < 4)
                                    lst[g] |= (unsigned long long)(unsigned)(kb + r)
                                              << (cnt[g] << 4);
                                ++cnt[g];
                            }
                        }
                    }
                }
            }
        }
    }
    {
        const int wq = wave * 4 + quad;
        #pragma unroll
        for (int g = 0; g < 4; ++g) {
            sCandL[wq][g * 16 + col] = lst[g];
            sCntL[wq][g * 16 + col]  = cnt[g];
        }
    }
    __syncthreads();

    // ---- rescue phase A: each wave exact-evals ITS candidate quads ---------
    //      (wq = 4*wave..4*wave+3, ascending disjoint k-ranges; identical
    //      per-candidate numerics to the R6 serial scan)
    {
        const int p = lane;
        int tot = 0, cmax = 0, mycnt = 0;
        #pragma unroll
        for (int wq = 0; wq < 16; ++wq) {
            int c = sCntL[wq][p];
            tot += c;
            cmax = c > cmax ? c : cmax;
            if ((wq >> 2) == wave) mycnt += c;
        }
        if (tot >= 2 && cmax <= 4) {
            float bd = 3.0e38f; int win = KCODES - 1;
            if (mycnt > 0) {
                const float* xin = inp + (size_t)b * DDIM * HW + (hw0 + p);
                float x[DDIM];
                #pragma unroll
                for (int d = 0; d < DDIM; ++d) x[d] = xin[(size_t)d * HW];
                const float A = sA[p];
                #pragma unroll 1
                for (int q = 0; q < 4; ++q) {
                    const int wq = wave * 4 + q;
                    int c = sCntL[wq][p];
                    unsigned long long L = sCandL[wq][p];
                    #pragma unroll 1
                    for (int i = 0; i < c; ++i) {       // ascending k order
                        int k = (int)(L & 0xffffu);
                        L >>= 16;
                        float e[DDIM];
                        const float4* e4 = (const float4*)(emb + (size_t)k * DDIM);
                        #pragma unroll
                        for (int j = 0; j < 16; ++j) ((float4*)e)[j] = e4[j];
                        float g = 0.f;
                        #pragma unroll
                        for (int d = 0; d < DDIM; ++d) g = fmaf(x[d], e[d], g);
                        float dd = __fadd_rn(__fsub_rn(A, __fmul_rn(2.0f, g)), Cw[k]);
                        if (dd < bd || (dd == bd && k < win)) { bd = dd; win = k; }
                    }
                }
            }
            sResB[wave][p] = bd;
            sResW[wave][p] = win;
        }
    }
    __syncthreads();

    // ---- rescue phase B: combine (tid<64); fast/fallback paths unchanged ---
    if (tid < PPB) {
        const int p = tid, n = base + p;
        int tot = 0, cmax = 0;
        #pragma unroll
        for (int wq = 0; wq < 16; ++wq) {
            int c = sCntL[wq][p];
            tot += c;
            cmax = c > cmax ? c : cmax;
        }
        int win;
        if (tot == 1) {
            win = 0;
            #pragma unroll
            for (int wq = 0; wq < 16; ++wq)
                if (sCntL[wq][p]) win = (int)(sCandL[wq][p] & 0xffffu);
        } else if (cmax <= 4) {
            float bd = 3.0e38f; win = KCODES - 1;
            #pragma unroll
            for (int w = 0; w < 4; ++w) {       // ascending k-range order
                float dw = sResB[w][p];
                int   ww = sResW[w][p];
                if (dw < bd || (dw == bd && ww < win)) { bd = dw; win = ww; }
            }
        } else {                                    // overflow safety
            const float* xin = inp + (size_t)b * DDIM * HW + (hw0 + p);
            float x[DDIM];
            #pragma unroll
            for (int d = 0; d < DDIM; ++d) x[d] = xin[(size_t)d * HW];
            const float A = sA[p];
            float bd = 3.0e38f; win = KCODES - 1;
            #pragma unroll 1
            for (int k = 0; k < KCODES; ++k) {
                float e[DDIM];
                const float4* e4 = (const float4*)(emb + (size_t)k * DDIM);
                #pragma unroll
                for (int j = 0; j < 16; ++j) ((float4*)e)[j] = e4[j];
                float g = 0.f;
                #pragma unroll
                for (int d = 0; d < DDIM; ++d) g = fmaf(x[d], e[d], g);
                float dd = __fadd_rn(__fsub_rn(A, __fmul_rn(2.0f, g)), Cw[k]);
                if (dd < bd) { bd = dd; win = k; }
            }
        }
        sWin[p] = win;
        out[OUT_IDX + n] = (float)win;
    }
    __syncthreads();

    // ---- epilogue: quantized NCHW + loss partial (plain store) -------------
    {
        const int pl = tid & 63, qtr = tid >> 6;
        const int win = sWin[pl];
        const int ch0 = qtr * 16;
        float q[16];
        const float4* q4 = (const float4*)(emb + (size_t)win * DDIM + ch0);
        #pragma unroll
        for (int j = 0; j < 4; ++j) ((float4*)q)[j] = q4[j];
        const size_t off = (size_t)b * DDIM * HW + (size_t)ch0 * HW + (hw0 + pl);
        const float* xin2 = inp + off;
        float* orow = out + off;
        float lacc = 0.f;
        #pragma unroll
        for (int j = 0; j < 16; ++j) {
            float xv = xin2[(size_t)j * HW];
            float diff = __fsub_rn(q[j], xv);
            orow[(size_t)j * HW] = __fadd_rn(xv, diff);   // ref's x + (q - x)
            lacc = fmaf(diff, diff, lacc);
        }
        #pragma unroll
        for (int o2 = 32; o2 > 0; o2 >>= 1) lacc += __shfl_down(lacc, o2, 64);
        if (lane == 0) sred[wave] = lacc;
    }
    __syncthreads();
    if (tid == 0)
        ws[WS_PART + blockIdx.x] = sred[0] + sred[1] + sred[2] + sred[3];
}

// 1 block x 256: reduce 1024 partials -> loss; write nll
__global__ __launch_bounds__(256) void vq_fin(const float* __restrict__ ws,
                                              float* __restrict__ out) {
    __shared__ float sred[4];
    const int tid = threadIdx.x;
    float s = 0.f;
    #pragma unroll
    for (int j = 0; j < 4; ++j) s += ws[WS_PART + j * 256 + tid];
    #pragma unroll
    for (int off = 32; off > 0; off >>= 1) s += __shfl_down(s, off, 64);
    if ((tid & 63) == 0) sred[tid >> 6] = s;
    __syncthreads();
    if (tid == 0) {
        float L = sred[0] + sred[1] + sred[2] + sred[3];
        out[OUT_LOSS] = L * (1.25f / 4194304.0f);   // (1+CC)*mean over N*D
        out[OUT_NLL]  = 1.0f;
    }
}

extern "C" void kernel_launch(void* const* d_in, const int* in_sizes, int n_in,
                              void* d_out, int out_size, void* d_ws, size_t ws_size,
                              hipStream_t stream) {
    const float* inp = (const float*)d_in[0];
    const float* emb = (const float*)d_in[1];
    float* out = (float*)d_out;
    float* ws  = (float*)d_ws;

    vq_init<<<16, 64, 0, stream>>>(emb, ws);
    vq_main<<<NBLK, 256, 0, stream>>>(inp, emb, ws, out);
    vq_fin<<<1, 256, 0, stream>>>(ws, out);
}